// Round 13
// baseline (90.504 us; speedup 1.0000x reference)
//
#include <hip/hip_runtime.h>

// Sizes: B=32, T=336, D=512, H=8, HD=64; M = B*T = 10752.
// hour classes: 24 classes x 14 members; day classes: 7 classes x 48 members
// (days dc and dc+7).

typedef __attribute__((ext_vector_type(8))) __bf16 bf16x8;
typedef __attribute__((ext_vector_type(8))) unsigned short u16x8;
typedef __attribute__((ext_vector_type(4))) float f32x4;

__device__ __forceinline__ unsigned short f2bf(float f) {
  union { float f; unsigned u; } v; v.f = f;
  unsigned r = v.u + 0x7fffu + ((v.u >> 16) & 1u);
  return (unsigned short)(r >> 16);
}
__device__ __forceinline__ unsigned pk2(float lo, float hi) {
  return (unsigned)f2bf(lo) | ((unsigned)f2bf(hi) << 16);
}

__device__ __forceinline__ void load_lds16(const void* g, void* l) {
  __builtin_amdgcn_global_load_lds(
      (const __attribute__((address_space(1))) void*)g,
      (__attribute__((address_space(3))) void*)l, 16, 0, 0);
}

// ---------------------------------------------------------------------------
// GEMM1 fused with x-cast: QKV = f2bf(x) @ WqkvT^T.
// A = x f32 [M][K] staged via regs (float4 loads -> f2bf pack -> ds_write,
// T14 issue-early/write-late), B = WqkvT bf16 [N][K] via global_load_lds.
// BM=64 x BN=128, BK=64, double-buffered, T2 chunk-XOR swizzle (both sides,
// rule #21), XCD-aware bijective block swizzle. MFMA operands bit-identical
// to the separate-cast version (same f2bf RNE) -> absmax unchanged.
// ---------------------------------------------------------------------------
__global__ __launch_bounds__(256) void gemm_xqkv(
    const float* __restrict__ X, const unsigned short* __restrict__ Bt,
    unsigned short* __restrict__ C, int M, int N, int K) {
  __shared__ __align__(16) unsigned short As[2 * 64 * 64];   // 2 x 8 KB
  __shared__ __align__(16) unsigned short Bs[2 * 128 * 64];  // 2 x 16 KB
  const int tid = threadIdx.x;
  const int lane = tid & 63;
  const int wid = tid >> 6;
  const int ntile = N >> 7;

  const int cpx = gridDim.x >> 3;
  const int bid = (blockIdx.x & 7) * cpx + (blockIdx.x >> 3);

  const int bx = bid % ntile;
  const int by = bid / ntile;
  const long row0 = (long)by << 6;   // BM = 64
  const long col0 = (long)bx << 7;   // BN = 128
  const int wr = (wid >> 1) << 5;
  const int wc = (wid & 1) << 6;

  // A staging: slot s (row r = s>>3, phys chunk c = s&7); source k-octet is
  // c ^ (r&7)  (involution, matches read-side XOR).
  const float* ax[2];
  int alofs[2];
#pragma unroll
  for (int it = 0; it < 2; ++it) {
    const int s = tid + (it << 8);   // 0..511
    const int r = s >> 3;
    const int c = s & 7;
    ax[it] = X + (row0 + r) * (long)K + ((c ^ (r & 7)) << 3);
    alofs[it] = s << 4;
  }
  const unsigned short* bg[4];
  int blofs[4];
#pragma unroll
  for (int it = 0; it < 4; ++it) {
    const int s = tid + (it << 8);   // 0..1023
    const int r = s >> 3;
    const int c = s & 7;
    bg[it] = Bt + (col0 + r) * (long)K + ((c ^ (r & 7)) << 3);
    blofs[it] = s << 4;
  }

  f32x4 acc[2][4];
  const f32x4 zero = {0.f, 0.f, 0.f, 0.f};
#pragma unroll
  for (int m = 0; m < 2; ++m)
#pragma unroll
    for (int n = 0; n < 4; ++n) acc[m][n] = zero;

  const int fr = lane & 15;
  const int grp = lane >> 4;
  const int sw = fr & 7;
  const int NT = K >> 6;

  // prologue: stage tile 0 into buffer 0
  {
#pragma unroll
    for (int it = 0; it < 4; ++it)
      load_lds16(bg[it], (char*)Bs + blofs[it]);
#pragma unroll
    for (int it = 0; it < 2; ++it) {
      const float4 a0 = *(const float4*)(ax[it]);
      const float4 a1 = *(const float4*)(ax[it] + 4);
      uint4 w;
      w.x = pk2(a0.x, a0.y); w.y = pk2(a0.z, a0.w);
      w.z = pk2(a1.x, a1.y); w.w = pk2(a1.z, a1.w);
      *(uint4*)((char*)As + alofs[it]) = w;
    }
  }
  __syncthreads();

  int cur = 0;
  for (int t = 0; t < NT; ++t) {
    float4 a0[2], a1[2];
    if (t + 1 < NT) {
      const int kk = (t + 1) << 6;
      const int nb = cur ^ 1;
      // issue loads early (hide under compute)
#pragma unroll
      for (int it = 0; it < 2; ++it) {
        a0[it] = *(const float4*)(ax[it] + kk);
        a1[it] = *(const float4*)(ax[it] + kk + 4);
      }
#pragma unroll
      for (int it = 0; it < 4; ++it)
        load_lds16(bg[it] + kk, (char*)Bs + nb * 16384 + blofs[it]);
    }
    // compute current tile
    const unsigned short* Ab = As + cur * 4096;
    const unsigned short* Bb = Bs + cur * 8192;
#pragma unroll
    for (int ks = 0; ks < 2; ++ks) {
      const int kc = ks * 4 + grp;
      bf16x8 a[2], b[4];
#pragma unroll
      for (int m = 0; m < 2; ++m) {
        const int row = wr + m * 16 + fr;
        a[m] = *(const bf16x8*)(const void*)(Ab + row * 64 + ((kc ^ sw) << 3));
      }
#pragma unroll
      for (int n = 0; n < 4; ++n) {
        const int row = wc + n * 16 + fr;
        b[n] = *(const bf16x8*)(const void*)(Bb + row * 64 + ((kc ^ sw) << 3));
      }
#pragma unroll
      for (int m = 0; m < 2; ++m)
#pragma unroll
        for (int n = 0; n < 4; ++n)
          acc[m][n] = __builtin_amdgcn_mfma_f32_16x16x32_bf16(a[m], b[n], acc[m][n], 0, 0, 0);
    }
    // write-late: convert & publish next A tile (nb != cur, race-free)
    if (t + 1 < NT) {
      const int nb = cur ^ 1;
#pragma unroll
      for (int it = 0; it < 2; ++it) {
        uint4 w;
        w.x = pk2(a0[it].x, a0[it].y); w.y = pk2(a0[it].z, a0[it].w);
        w.z = pk2(a1[it].x, a1[it].y); w.w = pk2(a1[it].z, a1[it].w);
        *(uint4*)((char*)As + nb * 8192 + alofs[it]) = w;
      }
    }
    __syncthreads();
    cur ^= 1;
  }

  // C/D layout: col = lane&15, row = (lane>>4)*4 + reg  [measured m89/m91]
  const int orow = (lane >> 4) << 2;
  const int ocol = lane & 15;
#pragma unroll
  for (int m = 0; m < 2; ++m) {
#pragma unroll
    for (int n = 0; n < 4; ++n) {
      const long gcol = col0 + wc + n * 16 + ocol;
#pragma unroll
      for (int r = 0; r < 4; ++r) {
        const long grow = row0 + wr + m * 16 + orow + r;
        C[grow * N + gcol] = f2bf(acc[m][n][r]);
      }
    }
  }
}

// ---------------------------------------------------------------------------
// GEMM2: out = comb @ WoT^T + bo. A bf16 via global_load_lds, BM=64 x BN=128,
// BK=64, double-buffered, T2 swizzle, XCD swizzle.
// (verified rounds 9-11, absmax 1.95e-3)
// ---------------------------------------------------------------------------
__global__ __launch_bounds__(256) void gemm_bt_f32(
    const unsigned short* __restrict__ A, const unsigned short* __restrict__ Bt,
    float* __restrict__ C, const float* __restrict__ bias, int M, int N, int K) {
  __shared__ __align__(16) unsigned short As[2 * 64 * 64];
  __shared__ __align__(16) unsigned short Bs[2 * 128 * 64];
  const int tid = threadIdx.x;
  const int lane = tid & 63;
  const int wid = tid >> 6;
  const int ntile = N >> 7;

  const int cpx = gridDim.x >> 3;
  const int bid = (blockIdx.x & 7) * cpx + (blockIdx.x >> 3);

  const int bx = bid % ntile;
  const int by = bid / ntile;
  const long row0 = (long)by << 6;
  const long col0 = (long)bx << 7;
  const int wr = (wid >> 1) << 5;
  const int wc = (wid & 1) << 6;

  const unsigned short* ag[2];
  const unsigned short* bg[4];
  int alofs[2], blofs[4];
#pragma unroll
  for (int it = 0; it < 2; ++it) {
    const int s = tid + (it << 8);
    const int r = s >> 3;
    const int c = s & 7;
    ag[it] = A + (row0 + r) * (long)K + ((c ^ (r & 7)) << 3);
    alofs[it] = s << 4;
  }
#pragma unroll
  for (int it = 0; it < 4; ++it) {
    const int s = tid + (it << 8);
    const int r = s >> 3;
    const int c = s & 7;
    bg[it] = Bt + (col0 + r) * (long)K + ((c ^ (r & 7)) << 3);
    blofs[it] = s << 4;
  }

  f32x4 acc[2][4];
  const f32x4 zero = {0.f, 0.f, 0.f, 0.f};
#pragma unroll
  for (int m = 0; m < 2; ++m)
#pragma unroll
    for (int n = 0; n < 4; ++n) acc[m][n] = zero;

  const int fr = lane & 15;
  const int grp = lane >> 4;
  const int sw = fr & 7;
  const int NT = K >> 6;

#pragma unroll
  for (int it = 0; it < 2; ++it)
    load_lds16(ag[it], (char*)As + alofs[it]);
#pragma unroll
  for (int it = 0; it < 4; ++it)
    load_lds16(bg[it], (char*)Bs + blofs[it]);
  __syncthreads();

  int cur = 0;
  for (int t = 0; t < NT; ++t) {
    if (t + 1 < NT) {
      const int kk = (t + 1) << 6;
      const int nb = cur ^ 1;
#pragma unroll
      for (int it = 0; it < 2; ++it)
        load_lds16(ag[it] + kk, (char*)As + nb * 8192 + alofs[it]);
#pragma unroll
      for (int it = 0; it < 4; ++it)
        load_lds16(bg[it] + kk, (char*)Bs + nb * 16384 + blofs[it]);
    }
    const unsigned short* Ab = As + cur * 4096;
    const unsigned short* Bb = Bs + cur * 8192;
#pragma unroll
    for (int ks = 0; ks < 2; ++ks) {
      const int kc = ks * 4 + grp;
      bf16x8 a[2], b[4];
#pragma unroll
      for (int m = 0; m < 2; ++m) {
        const int row = wr + m * 16 + fr;
        a[m] = *(const bf16x8*)(const void*)(Ab + row * 64 + ((kc ^ sw) << 3));
      }
#pragma unroll
      for (int n = 0; n < 4; ++n) {
        const int row = wc + n * 16 + fr;
        b[n] = *(const bf16x8*)(const void*)(Bb + row * 64 + ((kc ^ sw) << 3));
      }
#pragma unroll
      for (int m = 0; m < 2; ++m)
#pragma unroll
        for (int n = 0; n < 4; ++n)
          acc[m][n] = __builtin_amdgcn_mfma_f32_16x16x32_bf16(a[m], b[n], acc[m][n], 0, 0, 0);
    }
    __syncthreads();
    cur ^= 1;
  }

  const int orow = (lane >> 4) << 2;
  const int ocol = lane & 15;
#pragma unroll
  for (int m = 0; m < 2; ++m) {
#pragma unroll
    for (int n = 0; n < 4; ++n) {
      const long gcol = col0 + wc + n * 16 + ocol;
      const float bv = bias ? bias[gcol] : 0.f;
#pragma unroll
      for (int r = 0; r < 4; ++r) {
        const long grow = row0 + wr + m * 16 + orow + r;
        C[grow * N + gcol] = acc[m][n][r] + bv;
      }
    }
  }
}

// ---------------------------------------------------------------------------
// MFMA attention body, one wave per (b, h, class).
// MODE 0 = hour (14 members, t = c + 24*i), writes comb cols [0,512).
// MODE 1 = day (48 members, days dc & dc+7),   writes comb cols [512,1024).
// (verified: rounds 6-11, absmax 1.95e-3)
// ---------------------------------------------------------------------------
template <int MODE>
__device__ __forceinline__ void attn_body(
    const int cls, const int h, const int b, const int lane,
    const unsigned short* __restrict__ QKV, const float* __restrict__ bias,
    unsigned short* __restrict__ comb, unsigned short* smem) {
  constexpr int NQT = MODE ? 3 : 1;
  constexpr int NKT = MODE ? 3 : 1;
  constexpr int PVK = MODE ? 2 : 1;
  constexpr int MEM = MODE ? 48 : 14;
  constexpr int PLD = MODE ? 72 : 40;
  constexpr int VLD = MODE ? 72 : 40;
  constexpr int PE = 16 * NQT * PLD;
  constexpr int VE = 64 * VLD;

  unsigned short* P_lds = smem;
  unsigned short* Vt = smem + PE;
  const long rowBase = (long)b * 336;

  auto tmap = [&](int i) -> int {
    if (MODE) return 24 * cls + i + ((i < 24) ? 0 : 144);
    return cls + 24 * i;
  };

  {
    const uint4 z4 = {0u, 0u, 0u, 0u};
    uint4* p4 = (uint4*)P_lds;
#pragma unroll
    for (int i = 0; i < PE / 8 / 64 + 1; ++i) {
      const int idx = lane + i * 64;
      if (idx < PE / 8) p4[idx] = z4;
    }
    uint4* v4 = (uint4*)Vt;
#pragma unroll
    for (int i = 0; i < VE / 8 / 64 + 1; ++i) {
      const int idx = lane + i * 64;
      if (idx < VE / 8) v4[idx] = z4;
    }
  }
  __syncthreads();

  {
    const int kloc = lane >> 3;
    const int d0 = (lane & 7) * 8;
    constexpr int NPASS = (MEM + 7) / 8;
#pragma unroll
    for (int p = 0; p < NPASS; ++p) {
      const int k = p * 8 + kloc;
      if (k < MEM) {
        const long off = (rowBase + tmap(k)) * 1536 + 1024 + h * 64 + d0;
        const u16x8 vv = *(const u16x8*)(const void*)(QKV + off);
#pragma unroll
        for (int e = 0; e < 8; ++e) Vt[(d0 + e) * VLD + k] = vv[e];
      }
    }
  }

  const int fr = lane & 15;
  const int kgrp = (lane >> 4) << 3;
  bf16x8 aq[NQT][2], bk[NKT][2];
#pragma unroll
  for (int it = 0; it < NQT; ++it) {
    const int qi = 16 * it + fr;
    const long rq = (rowBase + tmap(qi < MEM ? qi : MEM - 1)) * 1536 + h * 64 + kgrp;
#pragma unroll
    for (int ks = 0; ks < 2; ++ks)
      aq[it][ks] = *(const bf16x8*)(const void*)(QKV + rq + ks * 32);
  }
#pragma unroll
  for (int jt = 0; jt < NKT; ++jt) {
    const int kj = 16 * jt + fr;
    const long rk = (rowBase + tmap(kj < MEM ? kj : MEM - 1)) * 1536 + 512 + h * 64 + kgrp;
#pragma unroll
    for (int ks = 0; ks < 2; ++ks)
      bk[jt][ks] = *(const bf16x8*)(const void*)(QKV + rk + ks * 32);
  }

  f32x4 sacc[NQT][NKT];
  const f32x4 zero = {0.f, 0.f, 0.f, 0.f};
#pragma unroll
  for (int it = 0; it < NQT; ++it)
#pragma unroll
    for (int jt = 0; jt < NKT; ++jt) sacc[it][jt] = zero;
#pragma unroll
  for (int ks = 0; ks < 2; ++ks)
#pragma unroll
    for (int it = 0; it < NQT; ++it)
#pragma unroll
      for (int jt = 0; jt < NKT; ++jt)
        sacc[it][jt] = __builtin_amdgcn_mfma_f32_16x16x32_bf16(aq[it][ks], bk[jt][ks], sacc[it][jt], 0, 0, 0);

  const int rgrp = (lane >> 4) << 2;
#pragma unroll
  for (int it = 0; it < NQT; ++it) {
#pragma unroll
    for (int r = 0; r < 4; ++r) {
      const int row = 16 * it + rgrp + r;
      const int tq = tmap(row < MEM ? row : MEM - 1);
      float sv[NKT];
#pragma unroll
      for (int jt = 0; jt < NKT; ++jt) {
        const int col = 16 * jt + fr;
        const int tk = tmap(col < MEM ? col : MEM - 1);
        sv[jt] = sacc[it][jt][r] * 0.125f + bias[(long)tq * 336 + tk];
        if (MODE == 0 && col >= MEM) sv[jt] = -1e30f;
      }
      float m = sv[0];
#pragma unroll
      for (int jt = 1; jt < NKT; ++jt) m = fmaxf(m, sv[jt]);
#pragma unroll
      for (int d = 1; d < 16; d <<= 1) m = fmaxf(m, __shfl_xor(m, d, 64));
      float e[NKT], sum = 0.f;
#pragma unroll
      for (int jt = 0; jt < NKT; ++jt) { e[jt] = __expf(sv[jt] - m); sum += e[jt]; }
#pragma unroll
      for (int d = 1; d < 16; d <<= 1) sum += __shfl_xor(sum, d, 64);
      const float inv = 1.f / sum;
#pragma unroll
      for (int jt = 0; jt < NKT; ++jt)
        P_lds[row * PLD + 16 * jt + fr] = f2bf(e[jt] * inv);
    }
  }
  __syncthreads();

  f32x4 oacc[NQT][4];
#pragma unroll
  for (int it = 0; it < NQT; ++it)
#pragma unroll
    for (int jt = 0; jt < 4; ++jt) oacc[it][jt] = zero;
#pragma unroll
  for (int ks = 0; ks < PVK; ++ks) {
    bf16x8 pa[NQT], vb[4];
#pragma unroll
    for (int it = 0; it < NQT; ++it)
      pa[it] = *(const bf16x8*)(const void*)(P_lds + (16 * it + fr) * PLD + ks * 32 + kgrp);
#pragma unroll
    for (int jt = 0; jt < 4; ++jt)
      vb[jt] = *(const bf16x8*)(const void*)(Vt + (16 * jt + fr) * VLD + ks * 32 + kgrp);
#pragma unroll
    for (int it = 0; it < NQT; ++it)
#pragma unroll
      for (int jt = 0; jt < 4; ++jt)
        oacc[it][jt] = __builtin_amdgcn_mfma_f32_16x16x32_bf16(pa[it], vb[jt], oacc[it][jt], 0, 0, 0);
  }

  const long colBase = (MODE ? 512 : 0) + h * 64;
#pragma unroll
  for (int it = 0; it < NQT; ++it) {
#pragma unroll
    for (int r = 0; r < 4; ++r) {
      const int row = 16 * it + rgrp + r;
      if (row < MEM) {
        const long base = (rowBase + tmap(row)) * 1024 + colBase;
#pragma unroll
        for (int jt = 0; jt < 4; ++jt)
          comb[base + 16 * jt + fr] = f2bf(oacc[it][jt][r]);
      }
    }
  }
}

// Fused hour+day attention (round-10 config, best measured): blocks
// [0,6144) = hour, [6144,7936) = day. LDS union 16128 B.
__global__ __launch_bounds__(64) void attn_all(
    const unsigned short* __restrict__ QKV, const float* __restrict__ rb,
    unsigned short* __restrict__ comb) {
  __shared__ __align__(16) unsigned short smem[8064];
  const int lane = threadIdx.x & 63;
  const int bi = blockIdx.x;
  if (bi < 6144) {
    const int c = bi % 24;
    const int h = (bi / 24) & 7;
    const int b = bi / (24 * 8);
    attn_body<0>(c, h, b, lane, QKV, rb, comb, smem);
  } else {
    const int di = bi - 6144;
    const int dc = di % 7;
    const int h = (di / 7) & 7;
    const int b = di / 56;
    attn_body<1>(dc, h, b, lane, QKV, rb + 336 * 336, comb, smem);
  }
}

// ---------------------------------------------------------------------------
// Weight casts only (x-cast now fused into gemm_xqkv)
// ---------------------------------------------------------------------------
__global__ __launch_bounds__(256) void cast_w(
    const float* __restrict__ Wq, const float* __restrict__ Wk,
    const float* __restrict__ Wv, const float* __restrict__ Wo,
    unsigned short* __restrict__ WqkvT, unsigned short* __restrict__ WoT) {
  const int g0 = blockIdx.x * 256 + threadIdx.x;
  const int gsz = gridDim.x * 256;
  // WqkvT [1536][512]: row n<512 -> Wq col n; 512..1023 -> Wk; else Wv.
  for (int idx = g0; idx < 1536 * 512; idx += gsz) {
    const int n = idx >> 9, k = idx & 511;
    const float* W = (n < 512) ? Wq : ((n < 1024) ? Wk : Wv);
    WqkvT[idx] = f2bf(W[k * 512 + (n & 511)]);
  }
  // WoT [512][1024] = transpose of Wo [1024][512]
  for (int idx = g0; idx < 512 * 1024; idx += gsz) {
    const int n = idx >> 10, k = idx & 1023;
    WoT[idx] = f2bf(Wo[k * 512 + n]);
  }
}

// ---------------------------------------------------------------------------
extern "C" void kernel_launch(void* const* d_in, const int* in_sizes, int n_in,
                              void* d_out, int out_size, void* d_ws, size_t ws_size,
                              hipStream_t stream) {
  (void)in_sizes; (void)n_in; (void)out_size; (void)ws_size;
  const float* x  = (const float*)d_in[0];
  const float* Wq = (const float*)d_in[1];
  const float* Wk = (const float*)d_in[2];
  const float* Wv = (const float*)d_in[3];
  const float* Wo = (const float*)d_in[4];
  const float* bo = (const float*)d_in[5];
  const float* rb = (const float*)d_in[6];

  char* ws = (char*)d_ws;
  unsigned short* WqkvT = (unsigned short*)(ws + 0);         // 1536*512*2  = 1,572,864
  unsigned short* WoT   = (unsigned short*)(ws + 1572864);   // 512*1024*2  = 1,048,576
  unsigned short* QKVb  = (unsigned short*)(ws + 2621440);   // 10752*1536*2 = 33,030,144
  unsigned short* comb  = (unsigned short*)(ws + 35651584);  // 10752*1024*2 = 22,020,096
  // total 57,671,680 bytes

  cast_w<<<1024, 256, 0, stream>>>(Wq, Wk, Wv, Wo, WqkvT, WoT);

  // QKV = f2bf(x) @ [Wq|Wk|Wv]  -> bf16 [10752][1536]  (2016 blocks, %8==0)
  gemm_xqkv<<<168 * 12, 256, 0, stream>>>(x, WqkvT, QKVb, 10752, 1536, 512);

  // hour (6144 blocks) + day (1792 blocks) fused
  attn_all<<<6144 + 1792, 64, 0, stream>>>(QKVb, rb, comb);

  // out = comb @ Wo + bo -> f32 [10752][512]  (672 blocks, %8==0)
  gemm_bt_f32<<<168 * 4, 256, 0, stream>>>(comb, WoT, (float*)d_out, bo, 10752, 512, 1024);
}

// Round 14
// 84.187 us; speedup vs baseline: 1.0750x; 1.0750x over previous
//
#include <hip/hip_runtime.h>

// Sizes: B=32, T=336, D=512, H=8, HD=64; M = B*T = 10752.
// hour classes: 24 classes x 14 members; day classes: 7 classes x 48 members
// (days dc and dc+7).

typedef __attribute__((ext_vector_type(8))) __bf16 bf16x8;
typedef __attribute__((ext_vector_type(8))) unsigned short u16x8;
typedef __attribute__((ext_vector_type(4))) float f32x4;

__device__ __forceinline__ unsigned short f2bf(float f) {
  union { float f; unsigned u; } v; v.f = f;
  unsigned r = v.u + 0x7fffu + ((v.u >> 16) & 1u);
  return (unsigned short)(r >> 16);
}

__device__ __forceinline__ void load_lds16(const void* g, void* l) {
  __builtin_amdgcn_global_load_lds(
      (const __attribute__((address_space(1))) void*)g,
      (__attribute__((address_space(3))) void*)l, 16, 0, 0);
}

// ---------------------------------------------------------------------------
// C = A [M][K] * Bt^T, Bt stored [N][K] (both bf16 row-major, k-contiguous).
// BM=64 x BN=128 tile, BK=64, min-2-phase double-buffered, T2 chunk-XOR
// swizzle (both-sides, rule #21), XCD-aware bijective block swizzle.
// (verified rounds 9/10, absmax 1.95e-3; round-13 lesson: keep A staging on
// global_load_lds — reg-staged fusion was 2x slower.)
// ---------------------------------------------------------------------------
template <bool OUT_BF16>
__global__ __launch_bounds__(256) void gemm_bt(
    const unsigned short* __restrict__ A, const unsigned short* __restrict__ Bt,
    void* __restrict__ Cv, const float* __restrict__ bias, int M, int N, int K) {
  __shared__ __align__(16) unsigned short As[2 * 64 * 64];   // 2 x 8 KB
  __shared__ __align__(16) unsigned short Bs[2 * 128 * 64];  // 2 x 16 KB
  const int tid = threadIdx.x;
  const int lane = tid & 63;
  const int wid = tid >> 6;
  const int ntile = N >> 7;

  const int cpx = gridDim.x >> 3;
  const int bid = (blockIdx.x & 7) * cpx + (blockIdx.x >> 3);

  const int bx = bid % ntile;
  const int by = bid / ntile;
  const long row0 = (long)by << 6;   // BM = 64
  const long col0 = (long)bx << 7;   // BN = 128
  const int wr = (wid >> 1) << 5;    // wave rows: 0 / 32
  const int wc = (wid & 1) << 6;     // wave cols: 0 / 64

  const unsigned short* ag[2];
  const unsigned short* bg[4];
  int alofs[2], blofs[4];
#pragma unroll
  for (int it = 0; it < 2; ++it) {
    const int s = tid + (it << 8);
    const int r = s >> 3;
    const int c = s & 7;
    ag[it] = A + (row0 + r) * (long)K + ((c ^ (r & 7)) << 3);
    alofs[it] = s << 4;
  }
#pragma unroll
  for (int it = 0; it < 4; ++it) {
    const int s = tid + (it << 8);
    const int r = s >> 3;
    const int c = s & 7;
    bg[it] = Bt + (col0 + r) * (long)K + ((c ^ (r & 7)) << 3);
    blofs[it] = s << 4;
  }

  f32x4 acc[2][4];
  const f32x4 zero = {0.f, 0.f, 0.f, 0.f};
#pragma unroll
  for (int m = 0; m < 2; ++m)
#pragma unroll
    for (int n = 0; n < 4; ++n) acc[m][n] = zero;

  const int fr = lane & 15;
  const int grp = lane >> 4;
  const int sw = fr & 7;

  const int NT = K >> 6;

#pragma unroll
  for (int it = 0; it < 2; ++it)
    load_lds16(ag[it], (char*)As + alofs[it]);
#pragma unroll
  for (int it = 0; it < 4; ++it)
    load_lds16(bg[it], (char*)Bs + blofs[it]);
  __syncthreads();

  int cur = 0;
  for (int t = 0; t < NT; ++t) {
    if (t + 1 < NT) {
      const int kk = (t + 1) << 6;
      const int nb = cur ^ 1;
#pragma unroll
      for (int it = 0; it < 2; ++it)
        load_lds16(ag[it] + kk, (char*)As + nb * 8192 + alofs[it]);
#pragma unroll
      for (int it = 0; it < 4; ++it)
        load_lds16(bg[it] + kk, (char*)Bs + nb * 16384 + blofs[it]);
    }
    const unsigned short* Ab = As + cur * 4096;
    const unsigned short* Bb = Bs + cur * 8192;
#pragma unroll
    for (int ks = 0; ks < 2; ++ks) {
      const int kc = ks * 4 + grp;
      bf16x8 a[2], b[4];
#pragma unroll
      for (int m = 0; m < 2; ++m) {
        const int row = wr + m * 16 + fr;
        a[m] = *(const bf16x8*)(const void*)(Ab + row * 64 + ((kc ^ sw) << 3));
      }
#pragma unroll
      for (int n = 0; n < 4; ++n) {
        const int row = wc + n * 16 + fr;
        b[n] = *(const bf16x8*)(const void*)(Bb + row * 64 + ((kc ^ sw) << 3));
      }
#pragma unroll
      for (int m = 0; m < 2; ++m)
#pragma unroll
        for (int n = 0; n < 4; ++n)
          acc[m][n] = __builtin_amdgcn_mfma_f32_16x16x32_bf16(a[m], b[n], acc[m][n], 0, 0, 0);
    }
    __syncthreads();
    cur ^= 1;
  }

  const int orow = (lane >> 4) << 2;
  const int ocol = lane & 15;
#pragma unroll
  for (int m = 0; m < 2; ++m) {
#pragma unroll
    for (int n = 0; n < 4; ++n) {
      const long gcol = col0 + wc + n * 16 + ocol;
      float bv = 0.f;
      if (!OUT_BF16 && bias) bv = bias[gcol];
#pragma unroll
      for (int r = 0; r < 4; ++r) {
        const long grow = row0 + wr + m * 16 + orow + r;
        const float val = acc[m][n][r] + bv;
        if (OUT_BF16)
          ((unsigned short*)Cv)[grow * N + gcol] = f2bf(val);
        else
          ((float*)Cv)[grow * N + gcol] = val;
      }
    }
  }
}

// ---------------------------------------------------------------------------
// MFMA attention body, one wave per (b, h, class).
// MODE 0 = hour (14 members, t = c + 24*i), writes comb cols [0,512).
// MODE 1 = day (48 members, days dc & dc+7),   writes comb cols [512,1024).
// (verified: rounds 6-11, absmax 1.95e-3)
// ---------------------------------------------------------------------------
template <int MODE>
__device__ __forceinline__ void attn_body(
    const int cls, const int h, const int b, const int lane,
    const unsigned short* __restrict__ QKV, const float* __restrict__ bias,
    unsigned short* __restrict__ comb, unsigned short* smem) {
  constexpr int NQT = MODE ? 3 : 1;
  constexpr int NKT = MODE ? 3 : 1;
  constexpr int PVK = MODE ? 2 : 1;
  constexpr int MEM = MODE ? 48 : 14;
  constexpr int PLD = MODE ? 72 : 40;
  constexpr int VLD = MODE ? 72 : 40;
  constexpr int PE = 16 * NQT * PLD;
  constexpr int VE = 64 * VLD;

  unsigned short* P_lds = smem;
  unsigned short* Vt = smem + PE;
  const long rowBase = (long)b * 336;

  auto tmap = [&](int i) -> int {
    if (MODE) return 24 * cls + i + ((i < 24) ? 0 : 144);
    return cls + 24 * i;
  };

  {
    const uint4 z4 = {0u, 0u, 0u, 0u};
    uint4* p4 = (uint4*)P_lds;
#pragma unroll
    for (int i = 0; i < PE / 8 / 64 + 1; ++i) {
      const int idx = lane + i * 64;
      if (idx < PE / 8) p4[idx] = z4;
    }
    uint4* v4 = (uint4*)Vt;
#pragma unroll
    for (int i = 0; i < VE / 8 / 64 + 1; ++i) {
      const int idx = lane + i * 64;
      if (idx < VE / 8) v4[idx] = z4;
    }
  }
  __syncthreads();

  {
    const int kloc = lane >> 3;
    const int d0 = (lane & 7) * 8;
    constexpr int NPASS = (MEM + 7) / 8;
#pragma unroll
    for (int p = 0; p < NPASS; ++p) {
      const int k = p * 8 + kloc;
      if (k < MEM) {
        const long off = (rowBase + tmap(k)) * 1536 + 1024 + h * 64 + d0;
        const u16x8 vv = *(const u16x8*)(const void*)(QKV + off);
#pragma unroll
        for (int e = 0; e < 8; ++e) Vt[(d0 + e) * VLD + k] = vv[e];
      }
    }
  }

  const int fr = lane & 15;
  const int kgrp = (lane >> 4) << 3;
  bf16x8 aq[NQT][2], bk[NKT][2];
#pragma unroll
  for (int it = 0; it < NQT; ++it) {
    const int qi = 16 * it + fr;
    const long rq = (rowBase + tmap(qi < MEM ? qi : MEM - 1)) * 1536 + h * 64 + kgrp;
#pragma unroll
    for (int ks = 0; ks < 2; ++ks)
      aq[it][ks] = *(const bf16x8*)(const void*)(QKV + rq + ks * 32);
  }
#pragma unroll
  for (int jt = 0; jt < NKT; ++jt) {
    const int kj = 16 * jt + fr;
    const long rk = (rowBase + tmap(kj < MEM ? kj : MEM - 1)) * 1536 + 512 + h * 64 + kgrp;
#pragma unroll
    for (int ks = 0; ks < 2; ++ks)
      bk[jt][ks] = *(const bf16x8*)(const void*)(QKV + rk + ks * 32);
  }

  f32x4 sacc[NQT][NKT];
  const f32x4 zero = {0.f, 0.f, 0.f, 0.f};
#pragma unroll
  for (int it = 0; it < NQT; ++it)
#pragma unroll
    for (int jt = 0; jt < NKT; ++jt) sacc[it][jt] = zero;
#pragma unroll
  for (int ks = 0; ks < 2; ++ks)
#pragma unroll
    for (int it = 0; it < NQT; ++it)
#pragma unroll
      for (int jt = 0; jt < NKT; ++jt)
        sacc[it][jt] = __builtin_amdgcn_mfma_f32_16x16x32_bf16(aq[it][ks], bk[jt][ks], sacc[it][jt], 0, 0, 0);

  const int rgrp = (lane >> 4) << 2;
#pragma unroll
  for (int it = 0; it < NQT; ++it) {
#pragma unroll
    for (int r = 0; r < 4; ++r) {
      const int row = 16 * it + rgrp + r;
      const int tq = tmap(row < MEM ? row : MEM - 1);
      float sv[NKT];
#pragma unroll
      for (int jt = 0; jt < NKT; ++jt) {
        const int col = 16 * jt + fr;
        const int tk = tmap(col < MEM ? col : MEM - 1);
        sv[jt] = sacc[it][jt][r] * 0.125f + bias[(long)tq * 336 + tk];
        if (MODE == 0 && col >= MEM) sv[jt] = -1e30f;
      }
      float m = sv[0];
#pragma unroll
      for (int jt = 1; jt < NKT; ++jt) m = fmaxf(m, sv[jt]);
#pragma unroll
      for (int d = 1; d < 16; d <<= 1) m = fmaxf(m, __shfl_xor(m, d, 64));
      float e[NKT], sum = 0.f;
#pragma unroll
      for (int jt = 0; jt < NKT; ++jt) { e[jt] = __expf(sv[jt] - m); sum += e[jt]; }
#pragma unroll
      for (int d = 1; d < 16; d <<= 1) sum += __shfl_xor(sum, d, 64);
      const float inv = 1.f / sum;
#pragma unroll
      for (int jt = 0; jt < NKT; ++jt)
        P_lds[row * PLD + 16 * jt + fr] = f2bf(e[jt] * inv);
    }
  }
  __syncthreads();

  f32x4 oacc[NQT][4];
#pragma unroll
  for (int it = 0; it < NQT; ++it)
#pragma unroll
    for (int jt = 0; jt < 4; ++jt) oacc[it][jt] = zero;
#pragma unroll
  for (int ks = 0; ks < PVK; ++ks) {
    bf16x8 pa[NQT], vb[4];
#pragma unroll
    for (int it = 0; it < NQT; ++it)
      pa[it] = *(const bf16x8*)(const void*)(P_lds + (16 * it + fr) * PLD + ks * 32 + kgrp);
#pragma unroll
    for (int jt = 0; jt < 4; ++jt)
      vb[jt] = *(const bf16x8*)(const void*)(Vt + (16 * jt + fr) * VLD + ks * 32 + kgrp);
#pragma unroll
    for (int it = 0; it < NQT; ++it)
#pragma unroll
      for (int jt = 0; jt < 4; ++jt)
        oacc[it][jt] = __builtin_amdgcn_mfma_f32_16x16x32_bf16(pa[it], vb[jt], oacc[it][jt], 0, 0, 0);
  }

  const long colBase = (MODE ? 512 : 0) + h * 64;
#pragma unroll
  for (int it = 0; it < NQT; ++it) {
#pragma unroll
    for (int r = 0; r < 4; ++r) {
      const int row = 16 * it + rgrp + r;
      if (row < MEM) {
        const long base = (rowBase + tmap(row)) * 1024 + colBase;
#pragma unroll
        for (int jt = 0; jt < 4; ++jt)
          comb[base + 16 * jt + fr] = f2bf(oacc[it][jt][r]);
      }
    }
  }
}

// Fused hour+day attention: blocks [0,6144) = hour, [6144,7936) = day.
// LDS union sized for day (8064 ushorts = 16128 B).
__global__ __launch_bounds__(64) void attn_all(
    const unsigned short* __restrict__ QKV, const float* __restrict__ rb,
    unsigned short* __restrict__ comb) {
  __shared__ __align__(16) unsigned short smem[8064];
  const int lane = threadIdx.x & 63;
  const int bi = blockIdx.x;
  if (bi < 6144) {
    const int c = bi % 24;
    const int h = (bi / 24) & 7;
    const int b = bi / (24 * 8);
    attn_body<0>(c, h, b, lane, QKV, rb, comb, smem);
  } else {
    const int di = bi - 6144;
    const int dc = di % 7;
    const int h = (di / 7) & 7;
    const int b = di / 56;
    attn_body<1>(dc, h, b, lane, QKV, rb + 336 * 336, comb, smem);
  }
}

// ---------------------------------------------------------------------------
// Fused casts (grid-stride over three jobs)
// ---------------------------------------------------------------------------
__global__ __launch_bounds__(256) void cast_all(
    const float* __restrict__ x, const float* __restrict__ Wq,
    const float* __restrict__ Wk, const float* __restrict__ Wv,
    const float* __restrict__ Wo, unsigned short* __restrict__ xb,
    unsigned short* __restrict__ WqkvT, unsigned short* __restrict__ WoT) {
  const int g0 = blockIdx.x * 256 + threadIdx.x;
  const int gsz = gridDim.x * 256;
  for (int i = g0; i < 1376256; i += gsz) {
    const float4 v = ((const float4*)x)[i];
    ushort4 o;
    o.x = f2bf(v.x); o.y = f2bf(v.y); o.z = f2bf(v.z); o.w = f2bf(v.w);
    ((ushort4*)xb)[i] = o;
  }
  for (int idx = g0; idx < 1536 * 512; idx += gsz) {
    const int n = idx >> 9, k = idx & 511;
    const float* W = (n < 512) ? Wq : ((n < 1024) ? Wk : Wv);
    WqkvT[idx] = f2bf(W[k * 512 + (n & 511)]);
  }
  for (int idx = g0; idx < 512 * 1024; idx += gsz) {
    const int n = idx >> 10, k = idx & 1023;
    WoT[idx] = f2bf(Wo[k * 512 + n]);
  }
}

// ---------------------------------------------------------------------------
extern "C" void kernel_launch(void* const* d_in, const int* in_sizes, int n_in,
                              void* d_out, int out_size, void* d_ws, size_t ws_size,
                              hipStream_t stream) {
  (void)in_sizes; (void)n_in; (void)out_size; (void)ws_size;
  const float* x  = (const float*)d_in[0];
  const float* Wq = (const float*)d_in[1];
  const float* Wk = (const float*)d_in[2];
  const float* Wv = (const float*)d_in[3];
  const float* Wo = (const float*)d_in[4];
  const float* bo = (const float*)d_in[5];
  const float* rb = (const float*)d_in[6];

  char* ws = (char*)d_ws;
  unsigned short* xbf   = (unsigned short*)(ws + 0);         // 10752*512*2  = 11,010,048
  unsigned short* WqkvT = (unsigned short*)(ws + 11010048);  // 1536*512*2   =  1,572,864
  unsigned short* WoT   = (unsigned short*)(ws + 12582912);  // 512*1024*2   =  1,048,576
  unsigned short* QKVb  = (unsigned short*)(ws + 13631488);  // 10752*1536*2 = 33,030,144
  unsigned short* comb  = (unsigned short*)(ws + 46661632);  // 10752*1024*2 = 22,020,096
  // total 68,681,728 bytes

  cast_all<<<2048, 256, 0, stream>>>(x, Wq, Wk, Wv, Wo, xbf, WqkvT, WoT);

  // QKV = x @ [Wq|Wk|Wv]  -> bf16 [10752][1536]   (168*12 = 2016 blocks, %8==0)
  gemm_bt<true><<<168 * 12, 256, 0, stream>>>(xbf, WqkvT, QKVb, nullptr, 10752, 1536, 512);

  // hour (6144 blocks) + day (1792 blocks) fused
  attn_all<<<6144 + 1792, 64, 0, stream>>>(QKVb, rb, comb);

  // out = comb @ Wo + bo -> f32 [10752][512]      (168*4 = 672 blocks, %8==0)
  gemm_bt<false><<<168 * 4, 256, 0, stream>>>(comb, WoT, d_out, bo, 10752, 512, 1024);
}

// Round 15
// 82.098 us; speedup vs baseline: 1.1024x; 1.0254x over previous
//
#include <hip/hip_runtime.h>

// Sizes: B=32, T=336, D=512, H=8, HD=64; M = B*T = 10752.
// hour classes: 24 classes x 14 members; day classes: 7 classes x 48 members
// (days dc and dc+7).

typedef __attribute__((ext_vector_type(8))) __bf16 bf16x8;
typedef __attribute__((ext_vector_type(8))) unsigned short u16x8;
typedef __attribute__((ext_vector_type(4))) float f32x4;

__device__ __forceinline__ unsigned short f2bf(float f) {
  union { float f; unsigned u; } v; v.f = f;
  unsigned r = v.u + 0x7fffu + ((v.u >> 16) & 1u);
  return (unsigned short)(r >> 16);
}

__device__ __forceinline__ void load_lds16(const void* g, void* l) {
  __builtin_amdgcn_global_load_lds(
      (const __attribute__((address_space(1))) void*)g,
      (__attribute__((address_space(3))) void*)l, 16, 0, 0);
}

// ---------------------------------------------------------------------------
// GEMM1: QKV = xbf @ WqkvT^T, bf16. 256x256 tile, BK=64, 8 waves (2Mx4N,
// wave = 128x64, acc 8x4), double-buffered (128 KB LDS -> 1 block/CU),
// T2 chunk-XOR swizzle (both sides, rule #21), T5 setprio around MFMA,
// m204 bijective XCD swizzle (grid 252, not %8). Post-compute vmcnt drain
// (loads land under 64 MFMA/wave). Same per-element accumulation order as
// the verified BM=64 kernel -> absmax bit-identical.
// ---------------------------------------------------------------------------
__global__ __launch_bounds__(512) void gemm1_big(
    const unsigned short* __restrict__ A, const unsigned short* __restrict__ Bt,
    unsigned short* __restrict__ C, int M, int N, int K) {
  __shared__ __align__(16) unsigned short As[2 * 256 * 64];  // 64 KB
  __shared__ __align__(16) unsigned short Bs[2 * 256 * 64];  // 64 KB
  const int tid = threadIdx.x;
  const int lane = tid & 63;
  const int wid = tid >> 6;          // 0..7
  const int ntile = N >> 8;          // 256-col tiles

  // m204 bijective XCD swizzle (works for any nwg)
  const int nwg = gridDim.x;
  const int q = nwg >> 3, r8 = nwg & 7;
  const int xcd = blockIdx.x & 7, io = blockIdx.x >> 3;
  const int bid = (xcd < r8 ? xcd * (q + 1) : r8 * (q + 1) + (xcd - r8) * q) + io;

  const int bx = bid % ntile;
  const int by = bid / ntile;
  const long row0 = (long)by << 8;   // BM = 256
  const long col0 = (long)bx << 8;   // BN = 256
  const int wr = (wid >> 2) << 7;    // 0 / 128
  const int wc = (wid & 3) << 6;     // 0 / 64 / 128 / 192

  // staging: slot s -> row rr = s>>3, phys 16B chunk cc = s&7; global source
  // k-octet = cc ^ (rr&7) (involution; matches read-side XOR).
  const unsigned short* ag[4];
  const unsigned short* bg[4];
  int lofs[4];
#pragma unroll
  for (int it = 0; it < 4; ++it) {
    const int s = tid + (it << 9);   // 0..2047
    const int rr = s >> 3;
    const int cc = s & 7;
    ag[it] = A + (row0 + rr) * (long)K + ((cc ^ (rr & 7)) << 3);
    bg[it] = Bt + (col0 + rr) * (long)K + ((cc ^ (rr & 7)) << 3);
    lofs[it] = s << 4;               // byte offset within one LDS buffer
  }

  f32x4 acc[8][4];
  const f32x4 zero = {0.f, 0.f, 0.f, 0.f};
#pragma unroll
  for (int m = 0; m < 8; ++m)
#pragma unroll
    for (int n = 0; n < 4; ++n) acc[m][n] = zero;

  const int fr = lane & 15;
  const int grp = lane >> 4;
  const int sw = fr & 7;
  const int NT = K >> 6;             // 8 for K=512

  // prologue: stage tile 0 into buffer 0
#pragma unroll
  for (int it = 0; it < 4; ++it) {
    load_lds16(ag[it], (char*)As + lofs[it]);
    load_lds16(bg[it], (char*)Bs + lofs[it]);
  }
  __syncthreads();

  int cur = 0;
  for (int t = 0; t < NT; ++t) {
    if (t + 1 < NT) {
      const int kk = (t + 1) << 6;
      const int nb = cur ^ 1;
#pragma unroll
      for (int it = 0; it < 4; ++it) {
        load_lds16(ag[it] + kk, (char*)As + nb * 32768 + lofs[it]);
        load_lds16(bg[it] + kk, (char*)Bs + nb * 32768 + lofs[it]);
      }
    }
    const unsigned short* Ab = As + cur * 16384;
    const unsigned short* Bb = Bs + cur * 16384;
#pragma unroll
    for (int ks = 0; ks < 2; ++ks) {
      const int kc = ks * 4 + grp;
      bf16x8 a[8], b[4];
#pragma unroll
      for (int m = 0; m < 8; ++m) {
        const int row = wr + m * 16 + fr;
        a[m] = *(const bf16x8*)(const void*)(Ab + row * 64 + ((kc ^ sw) << 3));
      }
#pragma unroll
      for (int n = 0; n < 4; ++n) {
        const int row = wc + n * 16 + fr;
        b[n] = *(const bf16x8*)(const void*)(Bb + row * 64 + ((kc ^ sw) << 3));
      }
      __builtin_amdgcn_s_setprio(1);
#pragma unroll
      for (int m = 0; m < 8; ++m)
#pragma unroll
        for (int n = 0; n < 4; ++n)
          acc[m][n] = __builtin_amdgcn_mfma_f32_16x16x32_bf16(a[m], b[n], acc[m][n], 0, 0, 0);
      __builtin_amdgcn_s_setprio(0);
    }
    // barrier's implicit vmcnt(0) drains the t+1 stage, which has been
    // landing under the 64 MFMAs above
    __syncthreads();
    cur ^= 1;
  }

  // C/D layout: col = lane&15, row = (lane>>4)*4 + reg  [measured m89/m91]
  const int orow = (lane >> 4) << 2;
  const int ocol = lane & 15;
#pragma unroll
  for (int m = 0; m < 8; ++m) {
#pragma unroll
    for (int n = 0; n < 4; ++n) {
      const long gcol = col0 + wc + n * 16 + ocol;
#pragma unroll
      for (int r = 0; r < 4; ++r) {
        const long grow = row0 + wr + m * 16 + orow + r;
        C[grow * N + gcol] = f2bf(acc[m][n][r]);
      }
    }
  }
}

// ---------------------------------------------------------------------------
// GEMM2: out = comb @ WoT^T + bo. BM=64 x BN=128, BK=64, dbuf, T2 swizzle,
// XCD swizzle (gridDim%8==0). (verified rounds 9-14, absmax 1.95e-3)
// ---------------------------------------------------------------------------
__global__ __launch_bounds__(256) void gemm_bt_f32(
    const unsigned short* __restrict__ A, const unsigned short* __restrict__ Bt,
    float* __restrict__ C, const float* __restrict__ bias, int M, int N, int K) {
  __shared__ __align__(16) unsigned short As[2 * 64 * 64];
  __shared__ __align__(16) unsigned short Bs[2 * 128 * 64];
  const int tid = threadIdx.x;
  const int lane = tid & 63;
  const int wid = tid >> 6;
  const int ntile = N >> 7;

  const int cpx = gridDim.x >> 3;
  const int bid = (blockIdx.x & 7) * cpx + (blockIdx.x >> 3);

  const int bx = bid % ntile;
  const int by = bid / ntile;
  const long row0 = (long)by << 6;
  const long col0 = (long)bx << 7;
  const int wr = (wid >> 1) << 5;
  const int wc = (wid & 1) << 6;

  const unsigned short* ag[2];
  const unsigned short* bg[4];
  int alofs[2], blofs[4];
#pragma unroll
  for (int it = 0; it < 2; ++it) {
    const int s = tid + (it << 8);
    const int r = s >> 3;
    const int c = s & 7;
    ag[it] = A + (row0 + r) * (long)K + ((c ^ (r & 7)) << 3);
    alofs[it] = s << 4;
  }
#pragma unroll
  for (int it = 0; it < 4; ++it) {
    const int s = tid + (it << 8);
    const int r = s >> 3;
    const int c = s & 7;
    bg[it] = Bt + (col0 + r) * (long)K + ((c ^ (r & 7)) << 3);
    blofs[it] = s << 4;
  }

  f32x4 acc[2][4];
  const f32x4 zero = {0.f, 0.f, 0.f, 0.f};
#pragma unroll
  for (int m = 0; m < 2; ++m)
#pragma unroll
    for (int n = 0; n < 4; ++n) acc[m][n] = zero;

  const int fr = lane & 15;
  const int grp = lane >> 4;
  const int sw = fr & 7;
  const int NT = K >> 6;

#pragma unroll
  for (int it = 0; it < 2; ++it)
    load_lds16(ag[it], (char*)As + alofs[it]);
#pragma unroll
  for (int it = 0; it < 4; ++it)
    load_lds16(bg[it], (char*)Bs + blofs[it]);
  __syncthreads();

  int cur = 0;
  for (int t = 0; t < NT; ++t) {
    if (t + 1 < NT) {
      const int kk = (t + 1) << 6;
      const int nb = cur ^ 1;
#pragma unroll
      for (int it = 0; it < 2; ++it)
        load_lds16(ag[it] + kk, (char*)As + nb * 8192 + alofs[it]);
#pragma unroll
      for (int it = 0; it < 4; ++it)
        load_lds16(bg[it] + kk, (char*)Bs + nb * 16384 + blofs[it]);
    }
    const unsigned short* Ab = As + cur * 4096;
    const unsigned short* Bb = Bs + cur * 8192;
#pragma unroll
    for (int ks = 0; ks < 2; ++ks) {
      const int kc = ks * 4 + grp;
      bf16x8 a[2], b[4];
#pragma unroll
      for (int m = 0; m < 2; ++m) {
        const int row = wr + m * 16 + fr;
        a[m] = *(const bf16x8*)(const void*)(Ab + row * 64 + ((kc ^ sw) << 3));
      }
#pragma unroll
      for (int n = 0; n < 4; ++n) {
        const int row = wc + n * 16 + fr;
        b[n] = *(const bf16x8*)(const void*)(Bb + row * 64 + ((kc ^ sw) << 3));
      }
#pragma unroll
      for (int m = 0; m < 2; ++m)
#pragma unroll
        for (int n = 0; n < 4; ++n)
          acc[m][n] = __builtin_amdgcn_mfma_f32_16x16x32_bf16(a[m], b[n], acc[m][n], 0, 0, 0);
    }
    __syncthreads();
    cur ^= 1;
  }

  const int orow = (lane >> 4) << 2;
  const int ocol = lane & 15;
#pragma unroll
  for (int m = 0; m < 2; ++m) {
#pragma unroll
    for (int n = 0; n < 4; ++n) {
      const long gcol = col0 + wc + n * 16 + ocol;
      const float bv = bias ? bias[gcol] : 0.f;
#pragma unroll
      for (int r = 0; r < 4; ++r) {
        const long grow = row0 + wr + m * 16 + orow + r;
        C[grow * N + gcol] = acc[m][n][r] + bv;
      }
    }
  }
}

// ---------------------------------------------------------------------------
// MFMA attention body, one wave per (b, h, class).
// (verified: rounds 6-14, absmax 1.95e-3; at HBM floor)
// ---------------------------------------------------------------------------
template <int MODE>
__device__ __forceinline__ void attn_body(
    const int cls, const int h, const int b, const int lane,
    const unsigned short* __restrict__ QKV, const float* __restrict__ bias,
    unsigned short* __restrict__ comb, unsigned short* smem) {
  constexpr int NQT = MODE ? 3 : 1;
  constexpr int NKT = MODE ? 3 : 1;
  constexpr int PVK = MODE ? 2 : 1;
  constexpr int MEM = MODE ? 48 : 14;
  constexpr int PLD = MODE ? 72 : 40;
  constexpr int VLD = MODE ? 72 : 40;
  constexpr int PE = 16 * NQT * PLD;
  constexpr int VE = 64 * VLD;

  unsigned short* P_lds = smem;
  unsigned short* Vt = smem + PE;
  const long rowBase = (long)b * 336;

  auto tmap = [&](int i) -> int {
    if (MODE) return 24 * cls + i + ((i < 24) ? 0 : 144);
    return cls + 24 * i;
  };

  {
    const uint4 z4 = {0u, 0u, 0u, 0u};
    uint4* p4 = (uint4*)P_lds;
#pragma unroll
    for (int i = 0; i < PE / 8 / 64 + 1; ++i) {
      const int idx = lane + i * 64;
      if (idx < PE / 8) p4[idx] = z4;
    }
    uint4* v4 = (uint4*)Vt;
#pragma unroll
    for (int i = 0; i < VE / 8 / 64 + 1; ++i) {
      const int idx = lane + i * 64;
      if (idx < VE / 8) v4[idx] = z4;
    }
  }
  __syncthreads();

  {
    const int kloc = lane >> 3;
    const int d0 = (lane & 7) * 8;
    constexpr int NPASS = (MEM + 7) / 8;
#pragma unroll
    for (int p = 0; p < NPASS; ++p) {
      const int k = p * 8 + kloc;
      if (k < MEM) {
        const long off = (rowBase + tmap(k)) * 1536 + 1024 + h * 64 + d0;
        const u16x8 vv = *(const u16x8*)(const void*)(QKV + off);
#pragma unroll
        for (int e = 0; e < 8; ++e) Vt[(d0 + e) * VLD + k] = vv[e];
      }
    }
  }

  const int fr = lane & 15;
  const int kgrp = (lane >> 4) << 3;
  bf16x8 aq[NQT][2], bk[NKT][2];
#pragma unroll
  for (int it = 0; it < NQT; ++it) {
    const int qi = 16 * it + fr;
    const long rq = (rowBase + tmap(qi < MEM ? qi : MEM - 1)) * 1536 + h * 64 + kgrp;
#pragma unroll
    for (int ks = 0; ks < 2; ++ks)
      aq[it][ks] = *(const bf16x8*)(const void*)(QKV + rq + ks * 32);
  }
#pragma unroll
  for (int jt = 0; jt < NKT; ++jt) {
    const int kj = 16 * jt + fr;
    const long rk = (rowBase + tmap(kj < MEM ? kj : MEM - 1)) * 1536 + 512 + h * 64 + kgrp;
#pragma unroll
    for (int ks = 0; ks < 2; ++ks)
      bk[jt][ks] = *(const bf16x8*)(const void*)(QKV + rk + ks * 32);
  }

  f32x4 sacc[NQT][NKT];
  const f32x4 zero = {0.f, 0.f, 0.f, 0.f};
#pragma unroll
  for (int it = 0; it < NQT; ++it)
#pragma unroll
    for (int jt = 0; jt < NKT; ++jt) sacc[it][jt] = zero;
#pragma unroll
  for (int ks = 0; ks < 2; ++ks)
#pragma unroll
    for (int it = 0; it < NQT; ++it)
#pragma unroll
      for (int jt = 0; jt < NKT; ++jt)
        sacc[it][jt] = __builtin_amdgcn_mfma_f32_16x16x32_bf16(aq[it][ks], bk[jt][ks], sacc[it][jt], 0, 0, 0);

  const int rgrp = (lane >> 4) << 2;
#pragma unroll
  for (int it = 0; it < NQT; ++it) {
#pragma unroll
    for (int r = 0; r < 4; ++r) {
      const int row = 16 * it + rgrp + r;
      const int tq = tmap(row < MEM ? row : MEM - 1);
      float sv[NKT];
#pragma unroll
      for (int jt = 0; jt < NKT; ++jt) {
        const int col = 16 * jt + fr;
        const int tk = tmap(col < MEM ? col : MEM - 1);
        sv[jt] = sacc[it][jt][r] * 0.125f + bias[(long)tq * 336 + tk];
        if (MODE == 0 && col >= MEM) sv[jt] = -1e30f;
      }
      float m = sv[0];
#pragma unroll
      for (int jt = 1; jt < NKT; ++jt) m = fmaxf(m, sv[jt]);
#pragma unroll
      for (int d = 1; d < 16; d <<= 1) m = fmaxf(m, __shfl_xor(m, d, 64));
      float e[NKT], sum = 0.f;
#pragma unroll
      for (int jt = 0; jt < NKT; ++jt) { e[jt] = __expf(sv[jt] - m); sum += e[jt]; }
#pragma unroll
      for (int d = 1; d < 16; d <<= 1) sum += __shfl_xor(sum, d, 64);
      const float inv = 1.f / sum;
#pragma unroll
      for (int jt = 0; jt < NKT; ++jt)
        P_lds[row * PLD + 16 * jt + fr] = f2bf(e[jt] * inv);
    }
  }
  __syncthreads();

  f32x4 oacc[NQT][4];
#pragma unroll
  for (int it = 0; it < NQT; ++it)
#pragma unroll
    for (int jt = 0; jt < 4; ++jt) oacc[it][jt] = zero;
#pragma unroll
  for (int ks = 0; ks < PVK; ++ks) {
    bf16x8 pa[NQT], vb[4];
#pragma unroll
    for (int it = 0; it < NQT; ++it)
      pa[it] = *(const bf16x8*)(const void*)(P_lds + (16 * it + fr) * PLD + ks * 32 + kgrp);
#pragma unroll
    for (int jt = 0; jt < 4; ++jt)
      vb[jt] = *(const bf16x8*)(const void*)(Vt + (16 * jt + fr) * VLD + ks * 32 + kgrp);
#pragma unroll
    for (int it = 0; it < NQT; ++it)
#pragma unroll
      for (int jt = 0; jt < 4; ++jt)
        oacc[it][jt] = __builtin_amdgcn_mfma_f32_16x16x32_bf16(pa[it], vb[jt], oacc[it][jt], 0, 0, 0);
  }

  const long colBase = (MODE ? 512 : 0) + h * 64;
#pragma unroll
  for (int it = 0; it < NQT; ++it) {
#pragma unroll
    for (int r = 0; r < 4; ++r) {
      const int row = 16 * it + rgrp + r;
      if (row < MEM) {
        const long base = (rowBase + tmap(row)) * 1024 + colBase;
#pragma unroll
        for (int jt = 0; jt < 4; ++jt)
          comb[base + 16 * jt + fr] = f2bf(oacc[it][jt][r]);
      }
    }
  }
}

// Fused hour+day attention: blocks [0,6144) = hour, [6144,7936) = day.
__global__ __launch_bounds__(64) void attn_all(
    const unsigned short* __restrict__ QKV, const float* __restrict__ rb,
    unsigned short* __restrict__ comb) {
  __shared__ __align__(16) unsigned short smem[8064];
  const int lane = threadIdx.x & 63;
  const int bi = blockIdx.x;
  if (bi < 6144) {
    const int c = bi % 24;
    const int h = (bi / 24) & 7;
    const int b = bi / (24 * 8);
    attn_body<0>(c, h, b, lane, QKV, rb, comb, smem);
  } else {
    const int di = bi - 6144;
    const int dc = di % 7;
    const int h = (di / 7) & 7;
    const int b = di / 56;
    attn_body<1>(dc, h, b, lane, QKV, rb + 336 * 336, comb, smem);
  }
}

// ---------------------------------------------------------------------------
// Fused casts (grid-stride over three jobs)
// ---------------------------------------------------------------------------
__global__ __launch_bounds__(256) void cast_all(
    const float* __restrict__ x, const float* __restrict__ Wq,
    const float* __restrict__ Wk, const float* __restrict__ Wv,
    const float* __restrict__ Wo, unsigned short* __restrict__ xb,
    unsigned short* __restrict__ WqkvT, unsigned short* __restrict__ WoT) {
  const int g0 = blockIdx.x * 256 + threadIdx.x;
  const int gsz = gridDim.x * 256;
  for (int i = g0; i < 1376256; i += gsz) {
    const float4 v = ((const float4*)x)[i];
    ushort4 o;
    o.x = f2bf(v.x); o.y = f2bf(v.y); o.z = f2bf(v.z); o.w = f2bf(v.w);
    ((ushort4*)xb)[i] = o;
  }
  for (int idx = g0; idx < 1536 * 512; idx += gsz) {
    const int n = idx >> 9, k = idx & 511;
    const float* W = (n < 512) ? Wq : ((n < 1024) ? Wk : Wv);
    WqkvT[idx] = f2bf(W[k * 512 + (n & 511)]);
  }
  for (int idx = g0; idx < 512 * 1024; idx += gsz) {
    const int n = idx >> 10, k = idx & 1023;
    WoT[idx] = f2bf(Wo[k * 512 + n]);
  }
}

// ---------------------------------------------------------------------------
extern "C" void kernel_launch(void* const* d_in, const int* in_sizes, int n_in,
                              void* d_out, int out_size, void* d_ws, size_t ws_size,
                              hipStream_t stream) {
  (void)in_sizes; (void)n_in; (void)out_size; (void)ws_size;
  const float* x  = (const float*)d_in[0];
  const float* Wq = (const float*)d_in[1];
  const float* Wk = (const float*)d_in[2];
  const float* Wv = (const float*)d_in[3];
  const float* Wo = (const float*)d_in[4];
  const float* bo = (const float*)d_in[5];
  const float* rb = (const float*)d_in[6];

  char* ws = (char*)d_ws;
  unsigned short* xbf   = (unsigned short*)(ws + 0);         // 10752*512*2  = 11,010,048
  unsigned short* WqkvT = (unsigned short*)(ws + 11010048);  // 1536*512*2   =  1,572,864
  unsigned short* WoT   = (unsigned short*)(ws + 12582912);  // 512*1024*2   =  1,048,576
  unsigned short* QKVb  = (unsigned short*)(ws + 13631488);  // 10752*1536*2 = 33,030,144
  unsigned short* comb  = (unsigned short*)(ws + 46661632);  // 10752*1024*2 = 22,020,096
  // total 68,681,728 bytes

  cast_all<<<2048, 256, 0, stream>>>(x, Wq, Wk, Wv, Wo, xbf, WqkvT, WoT);

  // QKV = xbf @ [Wq|Wk|Wv] -> bf16 [10752][1536]; 256x256 tiles: 42*6 = 252 blocks
  gemm1_big<<<252, 512, 0, stream>>>(xbf, WqkvT, QKVb, 10752, 1536, 512);

  // hour (6144 blocks) + day (1792 blocks) fused
  attn_all<<<6144 + 1792, 64, 0, stream>>>(QKVb, rb, comb);

  // out = comb @ Wo + bo -> f32 [10752][512]  (672 blocks, %8==0)
  gemm_bt_f32<<<168 * 4, 256, 0, stream>>>(comb, WoT, (float*)d_out, bo, 10752, 512, 1024);
}